// Round 4
// baseline (118.177 us; speedup 1.0000x reference)
//
#include <hip/hip_runtime.h>
#include <math.h>

// B=4096, K=128, D=256.
// out[b,d] = sqrt(1-e) * sum_k p_k * (x - a*c)/var,  var = 1 + e*(s^2-1)
// lp_k = -0.5*S1 - 128*ln2*S2 + ln w_k  (k-uniform const dropped)
//   S1 = sum_d diff^2/var, S2 = sum_d log2(var)
// Quad-combined division (1 rcp / 4 d-tuples) + packed 2xf32 math (f2 lanes =
// 2 batch rows). G=2 -> 2048 blocks = 8 blocks/CU: grid-limited occupancy fix.

constexpr int Kc = 128;
constexpr int Dc = 256;
constexpr int G  = 2;   // batch rows per block (one f2 pair)

typedef float f2 __attribute__((ext_vector_type(2)));
typedef float f4 __attribute__((ext_vector_type(4)));

static __device__ __forceinline__ f2 fma2(f2 a, f2 b, f2 c) {
    return __builtin_elementwise_fma(a, b, c);
}
static __device__ __forceinline__ f2 splat2(float s) { return (f2){s, s}; }

// prep: CA8[(d>>2)][k][8] = {c0,c1,c2,c3,A0,A1,A2,A3} (pass-1, transposed);
//       P2[k*Dc+d] = {c, A} (pass-2), A = s^2-1.
__global__ void prep_kernel(const float* __restrict__ centers,
                            const float* __restrict__ stds,
                            float* __restrict__ CA8, f2* __restrict__ P2) {
    int idx = blockIdx.x * blockDim.x + threadIdx.x;   // k*Dc + d, read-coalesced
    if (idx >= Kc * Dc) return;
    int k = idx >> 8;
    int d = idx & (Dc - 1);
    float c = centers[idx];
    float s = stds[idx];
    float A = s * s - 1.0f;
    int o = (d >> 2) * (Kc * 8) + k * 8 + (d & 3);
    CA8[o]     = c;
    CA8[o + 4] = A;
    P2[idx] = (f2){c, A};
}

__global__ __launch_bounds__(256, 8) void score_kernel(
    const float* __restrict__ x, const float* __restrict__ t,
    const float* __restrict__ weights,
    const float* __restrict__ CA8, const f2* __restrict__ P2,
    float* __restrict__ out)
{
    const int b0  = blockIdx.x * G;
    const int tid = threadIdx.x;

    __shared__ __align__(16) f2 xT[Dc];        // x pair-transposed: xT[d] = {x0,x1}
    __shared__ float part1[G][2][Kc];
    __shared__ float partL[G][2][Kc];
    __shared__ __align__(16) f2 peT[Kc];       // unnormalized softmax numerators
    __shared__ float wmax[G][2];
    __shared__ float wsum[G][2];

    // per-row scalars
    float e[G], na[G], sg[G];
    #pragma unroll
    for (int g = 0; g < G; ++g) {
        float tt = t[b0 + g];
        float Bt = fmaf(9.95f * tt, tt, 0.1f * tt);
        float ee = __expf(-Bt);
        e[g]  = ee;
        na[g] = -sqrtf(ee);
        sg[g] = sqrtf(1.0f - ee);
    }
    const f2 e2   = {e[0], e[1]};
    const f2 na2  = {na[0], na[1]};
    const f2 one2 = {1.0f, 1.0f};

    {
        float x0 = x[(b0 + 0) * Dc + tid];     // coalesced
        float x1 = x[(b0 + 1) * Dc + tid];
        xT[tid] = (f2){x0, x1};                // b64 store, stride 8B: conflict-free
    }
    __syncthreads();

    // ---------------- pass 1: thread = (k, half-of-D) ----------------
    const int kk    = tid & (Kc - 1);
    const int half  = tid >> 7;
    const int dbase = half * (Dc / 2);

    const f4* xTv = (const f4*)(&xT[0]);       // one f4 = two d's, both g's

    f2 acc1 = {0.f, 0.f};
    float accL0 = 0.f, accL1 = 0.f;

    for (int grp = 0; grp < 8; ++grp) {
        f2 prod = {1.f, 1.f};
        #pragma unroll
        for (int q = 0; q < 4; ++q) {
            const int d0 = dbase + (grp * 4 + q) * 4;
            const float* base = CA8 + ((size_t)(d0 >> 2) * Kc + kk) * 8;
            f4 c4 = *(const f4*)base;          // dwordx4, coalesced over kk
            f4 A4 = *(const f4*)(base + 4);    // same addr + imm 16
            f4 xa = xTv[(d0 >> 1) + 0];        // LDS b128 broadcast (d uniform)
            f4 xb = xTv[(d0 >> 1) + 1];
            f2 x0 = {xa[0], xa[1]};
            f2 x1 = {xa[2], xa[3]};
            f2 x2 = {xb[0], xb[1]};
            f2 x3 = {xb[2], xb[3]};
            f2 v0 = fma2(e2, splat2(A4[0]), one2);   // var in [0.25,1]
            f2 v1 = fma2(e2, splat2(A4[1]), one2);
            f2 v2 = fma2(e2, splat2(A4[2]), one2);
            f2 v3 = fma2(e2, splat2(A4[3]), one2);
            f2 f0 = fma2(na2, splat2(c4[0]), x0);
            f2 f1 = fma2(na2, splat2(c4[1]), x1);
            f2 f2_ = fma2(na2, splat2(c4[2]), x2);
            f2 f3 = fma2(na2, splat2(c4[3]), x3);
            f2 s0 = f0 * f0, s1 = f1 * f1, s2 = f2_ * f2_, s3 = f3 * f3;
            f2 d01 = v0 * v1, d23 = v2 * v3;
            f2 n01 = fma2(s1, v0, s0 * v1);
            f2 n23 = fma2(s3, v2, s2 * v3);
            f2 den = d01 * d23;                      // >= 0.25^4
            f2 num = fma2(n23, d01, n01 * d23);
            f2 r = {__builtin_amdgcn_rcpf(den[0]),
                    __builtin_amdgcn_rcpf(den[1])};
            acc1 = fma2(num, r, acc1);
            prod = prod * den;
        }
        accL0 += __log2f(prod[0]);             // 1 log per 16 d per g
        accL1 += __log2f(prod[1]);
    }
    part1[0][half][kk] = acc1[0];
    part1[1][half][kk] = acc1[1];
    partL[0][half][kk] = accL0;
    partL[1][half][kk] = accL1;
    __syncthreads();

    // ---------------- softmax over k (threads < K, 2 full waves) ----------------
    float lpv[G];
    if (tid < Kc) {
        float lw = __logf(weights[tid]);
        #pragma unroll
        for (int g = 0; g < G; ++g) {
            float S1 = part1[g][0][tid] + part1[g][1][tid];
            float S2 = partL[g][0][tid] + partL[g][1][tid];
            lpv[g] = fmaf(-0.5f, S1, fmaf(-88.72283911167299f, S2, lw)); // 128*ln2
            float m = lpv[g];
            #pragma unroll
            for (int off = 32; off > 0; off >>= 1)
                m = fmaxf(m, __shfl_xor(m, off, 64));
            if ((tid & 63) == 0) wmax[g][tid >> 6] = m;
        }
    }
    __syncthreads();
    if (tid < Kc) {
        f2 pe2;
        #pragma unroll
        for (int g = 0; g < G; ++g) {
            float m  = fmaxf(wmax[g][0], wmax[g][1]);
            float pe = __expf(lpv[g] - m);
            pe2[g] = pe;
            float s = pe;
            #pragma unroll
            for (int off = 32; off > 0; off >>= 1)
                s += __shfl_xor(s, off, 64);
            if ((tid & 63) == 0) wsum[g][tid >> 6] = s;
        }
        peT[tid] = pe2;                        // unnormalized; 1/Z in epilogue
    }
    __syncthreads();

    // ---------------- pass 2: thread = d ----------------
    f2 xp = xT[tid];
    f2 O = {0.f, 0.f};
    const f4* peTv = (const f4*)(&peT[0]);     // one f4 = two k's, both g's
    const f2* pp = P2 + tid;

    for (int kq = 0; kq < 32; ++kq) {
        const int k0 = kq * 4;
        f2 ca0 = pp[(k0 + 0) * Dc];            // dwordx2 {c,A}, coalesced
        f2 ca1 = pp[(k0 + 1) * Dc];
        f2 ca2 = pp[(k0 + 2) * Dc];
        f2 ca3 = pp[(k0 + 3) * Dc];
        f4 pa = peTv[(k0 >> 1) + 0];           // LDS b128 broadcast
        f4 pb = peTv[(k0 >> 1) + 1];
        f2 p0 = {pa[0], pa[1]};
        f2 p1 = {pa[2], pa[3]};
        f2 p2 = {pb[0], pb[1]};
        f2 p3 = {pb[2], pb[3]};
        f2 v0 = fma2(e2, splat2(ca0[1]), one2);
        f2 v1 = fma2(e2, splat2(ca1[1]), one2);
        f2 v2 = fma2(e2, splat2(ca2[1]), one2);
        f2 v3 = fma2(e2, splat2(ca3[1]), one2);
        f2 f0 = fma2(na2, splat2(ca0[0]), xp);
        f2 f1 = fma2(na2, splat2(ca1[0]), xp);
        f2 f2_ = fma2(na2, splat2(ca2[0]), xp);
        f2 f3 = fma2(na2, splat2(ca3[0]), xp);
        f2 u0 = p0 * f0;
        f2 u1 = p1 * f1;
        f2 u2 = p2 * f2_;
        f2 u3 = p3 * f3;
        f2 d01 = v0 * v1, d23 = v2 * v3;
        f2 n01 = fma2(u1, v0, u0 * v1);
        f2 n23 = fma2(u3, v2, u2 * v3);
        f2 den = d01 * d23;
        f2 num = fma2(n23, d01, n01 * d23);
        f2 r = {__builtin_amdgcn_rcpf(den[0]),
                __builtin_amdgcn_rcpf(den[1])};
        O = fma2(num, r, O);
    }

    #pragma unroll
    for (int g = 0; g < G; ++g) {
        float Z = wsum[g][0] + wsum[g][1];
        out[(b0 + g) * Dc + tid] = sg[g] * __builtin_amdgcn_rcpf(Z) * O[g];
    }
}

extern "C" void kernel_launch(void* const* d_in, const int* in_sizes, int n_in,
                              void* d_out, int out_size, void* d_ws, size_t ws_size,
                              hipStream_t stream) {
    const float* x       = (const float*)d_in[0];
    const float* t       = (const float*)d_in[1];
    const float* centers = (const float*)d_in[2];
    const float* stds    = (const float*)d_in[3];
    const float* weights = (const float*)d_in[4];
    float* outp = (float*)d_out;

    float* CA8 = (float*)d_ws;                    // [D/4][K][8]  (256 KB)
    f2*    P2  = (f2*)(CA8 + Kc * Dc * 2);        // [K][D] {c,A} (256 KB)

    const int B = in_sizes[1];                    // 4096

    prep_kernel<<<(Kc * Dc + 255) / 256, 256, 0, stream>>>(centers, stds, CA8, P2);
    score_kernel<<<B / G, 256, 0, stream>>>(x, t, weights, CA8, P2, outp);
}

// Round 5
// 106.792 us; speedup vs baseline: 1.1066x; 1.1066x over previous
//
#include <hip/hip_runtime.h>
#include <math.h>

// B=4096, K=128, D=256.
// out[b,d] = sqrt(1-e) * sum_k p_k * (x - a*c)/var,  var = 1 + e*(s^2-1)
// lp_k = -0.5*S1 - 128*ln2*S2 + ln w_k  (k-uniform const dropped)
// The ndim/2=128 coefficient makes lp spread across k ~hundreds of nats ->
// softmax is near-one-hot: pass 2 iterates only survivor k's (lp >= m-25;
// dropped mass < 1e-8, exact-safe; worst case = full loop, still pairwise-
// combined so it matches the old pass-2 cost).
// Pass 1: packed 2xf32 math (f2 = 2 batch rows), 8-way combined division
// (1 rcp per 8 d-tuples), 1 log per 32 d. G=4 / 1024 blocks (R3 optimum:
// G=2/2048 doubled L2 traffic and regressed).

constexpr int Kc = 128;
constexpr int Dc = 256;
constexpr int G  = 4;   // batch rows per block (2 f2 pairs)

typedef float f2 __attribute__((ext_vector_type(2)));
typedef float f4 __attribute__((ext_vector_type(4)));

static __device__ __forceinline__ f2 fma2(f2 a, f2 b, f2 c) {
    return __builtin_elementwise_fma(a, b, c);
}
static __device__ __forceinline__ f2 splat2(float s) { return (f2){s, s}; }
static __device__ __forceinline__ f2 rcp2(f2 a) {
    return (f2){__builtin_amdgcn_rcpf(a[0]), __builtin_amdgcn_rcpf(a[1])};
}

// prep: CA8[(d>>2)][k][8] = {c0..c3, A0..A3} (pass-1, transposed);
//       P2[k*Dc+d] = {c, A} (pass-2), A = s^2-1.
__global__ void prep_kernel(const float* __restrict__ centers,
                            const float* __restrict__ stds,
                            float* __restrict__ CA8, f2* __restrict__ P2) {
    int idx = blockIdx.x * blockDim.x + threadIdx.x;   // k*Dc + d
    if (idx >= Kc * Dc) return;
    int k = idx >> 8;
    int d = idx & (Dc - 1);
    float c = centers[idx];
    float s = stds[idx];
    float A = s * s - 1.0f;
    int o = (d >> 2) * (Kc * 8) + k * 8 + (d & 3);
    CA8[o]     = c;
    CA8[o + 4] = A;
    P2[idx] = (f2){c, A};
}

__global__ __launch_bounds__(256, 4) void score_kernel(
    const float* __restrict__ x, const float* __restrict__ t,
    const float* __restrict__ weights,
    const float* __restrict__ CA8, const f2* __restrict__ P2,
    float* __restrict__ out)
{
    const int b0  = blockIdx.x * G;
    const int tid = threadIdx.x;

    __shared__ __align__(16) f4 xT[Dc];        // xT[d] = {x_g0..x_g3}
    __shared__ float part1[G][2][Kc];
    __shared__ float partL[G][2][Kc];
    __shared__ __align__(16) f4 peT[Kc];       // unnormalized softmax numerators
    __shared__ float wmax[G][2];
    __shared__ float wsum[G][2];
    __shared__ int wcnt[2];
    __shared__ int klist[Kc];
    __shared__ int nk_s;

    // per-row scalars
    float e[G], na[G], sg[G];
    #pragma unroll
    for (int g = 0; g < G; ++g) {
        float tt = t[b0 + g];
        float Bt = fmaf(9.95f * tt, tt, 0.1f * tt);
        float ee = __expf(-Bt);
        e[g]  = ee;
        na[g] = -sqrtf(ee);
        sg[g] = sqrtf(1.0f - ee);
    }
    f2 e2[2]  = {{e[0], e[1]}, {e[2], e[3]}};
    f2 na2[2] = {{na[0], na[1]}, {na[2], na[3]}};
    const f2 one2 = {1.0f, 1.0f};

    {
        f4 xv;
        #pragma unroll
        for (int g = 0; g < G; ++g) xv[g] = x[(b0 + g) * Dc + tid];
        xT[tid] = xv;
    }
    __syncthreads();

    // ---------------- pass 1: thread = (k, half-of-D) ----------------
    const int kk    = tid & (Kc - 1);
    const int half  = tid >> 7;
    const int dbase = half * (Dc / 2);

    const f4* xTv = (const f4*)(&xT[0]);

    f2 acc1[2] = {{0.f, 0.f}, {0.f, 0.f}};
    float accL[G] = {0.f, 0.f, 0.f, 0.f};

    for (int u4 = 0; u4 < 4; ++u4) {           // 4 x (4 units x 8 d) = 128 d
        f2 prod[2] = {{1.f, 1.f}, {1.f, 1.f}};
        #pragma unroll
        for (int uu = 0; uu < 4; ++uu) {
            const int d0 = dbase + (u4 * 4 + uu) * 8;
            f2 num8[2], den8[2];
            #pragma unroll
            for (int h = 0; h < 2; ++h) {      // two quads per unit
                const int dq = d0 + h * 4;
                const float* base = CA8 + ((size_t)(dq >> 2) * Kc + kk) * 8;
                f4 c4 = *(const f4*)base;      // dwordx4, coalesced over kk
                f4 A4 = *(const f4*)(base + 4);
                f4 xv0 = xTv[dq + 0];          // LDS b128 broadcast
                f4 xv1 = xTv[dq + 1];
                f4 xv2 = xTv[dq + 2];
                f4 xv3 = xTv[dq + 3];
                #pragma unroll
                for (int p = 0; p < 2; ++p) {
                    f2 ep = e2[p], nap = na2[p];
                    f2 x0 = {xv0[2*p], xv0[2*p+1]};
                    f2 x1 = {xv1[2*p], xv1[2*p+1]};
                    f2 x2 = {xv2[2*p], xv2[2*p+1]};
                    f2 x3 = {xv3[2*p], xv3[2*p+1]};
                    f2 v0 = fma2(ep, splat2(A4[0]), one2);   // var in [0.25,1]
                    f2 v1 = fma2(ep, splat2(A4[1]), one2);
                    f2 v2 = fma2(ep, splat2(A4[2]), one2);
                    f2 v3 = fma2(ep, splat2(A4[3]), one2);
                    f2 f0 = fma2(nap, splat2(c4[0]), x0);
                    f2 f1 = fma2(nap, splat2(c4[1]), x1);
                    f2 f2_ = fma2(nap, splat2(c4[2]), x2);
                    f2 f3 = fma2(nap, splat2(c4[3]), x3);
                    f2 s0 = f0 * f0, s1 = f1 * f1, s2 = f2_ * f2_, s3 = f3 * f3;
                    f2 d01 = v0 * v1, d23 = v2 * v3;
                    f2 n01 = fma2(s1, v0, s0 * v1);
                    f2 n23 = fma2(s3, v2, s2 * v3);
                    f2 den = d01 * d23;
                    f2 num = fma2(n23, d01, n01 * d23);
                    if (h == 0) { num8[p] = num; den8[p] = den; }
                    else {
                        f2 dU = den8[p] * den;               // >= 0.25^8
                        f2 nU = fma2(num, den8[p], num8[p] * den);
                        acc1[p] = fma2(nU, rcp2(dU), acc1[p]);
                        prod[p] = prod[p] * dU;
                    }
                }
            }
        }
        accL[0] += __log2f(prod[0][0]);        // prod >= 0.25^32 > FLT_MIN
        accL[1] += __log2f(prod[0][1]);
        accL[2] += __log2f(prod[1][0]);
        accL[3] += __log2f(prod[1][1]);
    }
    #pragma unroll
    for (int p = 0; p < 2; ++p) {
        part1[2*p  ][half][kk] = acc1[p][0];
        part1[2*p+1][half][kk] = acc1[p][1];
    }
    #pragma unroll
    for (int g = 0; g < G; ++g)
        partL[g][half][kk] = accL[g];
    __syncthreads();

    // ---------------- softmax over k + survivor compaction ----------------
    float lpv[G];
    bool flag = false;
    int myoff = 0;
    if (tid < Kc) {
        float lw = __logf(weights[tid]);
        #pragma unroll
        for (int g = 0; g < G; ++g) {
            float S1 = part1[g][0][tid] + part1[g][1][tid];
            float S2 = partL[g][0][tid] + partL[g][1][tid];
            lpv[g] = fmaf(-0.5f, S1, fmaf(-88.72283911167299f, S2, lw)); // 128*ln2
            float m = lpv[g];
            #pragma unroll
            for (int off = 32; off > 0; off >>= 1)
                m = fmaxf(m, __shfl_xor(m, off, 64));
            if ((tid & 63) == 0) wmax[g][tid >> 6] = m;
        }
    }
    __syncthreads();
    if (tid < Kc) {
        f4 pe4;
        #pragma unroll
        for (int g = 0; g < G; ++g) {
            float m  = fmaxf(wmax[g][0], wmax[g][1]);
            float pe = __expf(lpv[g] - m);
            pe4[g] = pe;
            flag |= (lpv[g] >= m - 25.0f);     // e^-25: dropped mass < 1e-8
            float s = pe;
            #pragma unroll
            for (int off = 32; off > 0; off >>= 1)
                s += __shfl_xor(s, off, 64);
            if ((tid & 63) == 0) wsum[g][tid >> 6] = s;
        }
        peT[tid] = pe4;
        unsigned long long msk = __ballot(flag);
        int lane = tid & 63;
        if (lane == 0) wcnt[tid >> 6] = __popcll(msk);
        myoff = __popcll(msk & ((1ull << lane) - 1ull));
    }
    __syncthreads();
    if (tid < Kc) {
        if (flag) {
            int basei = (tid >= 64) ? wcnt[0] : 0;
            klist[basei + myoff] = tid;
        }
        if (tid == 0) nk_s = wcnt[0] + wcnt[1];
    }
    __syncthreads();

    // ---------------- pass 2: thread = d, survivors only ----------------
    const int nk = nk_s;
    f4 xv = xT[tid];
    f2 xp[2] = {{xv[0], xv[1]}, {xv[2], xv[3]}};
    f2 O[2] = {{0.f, 0.f}, {0.f, 0.f}};
    const f2* pp = P2 + tid;

    for (int i = 0; i < nk; i += 2) {
        int ka = klist[i];
        bool hasb = (i + 1 < nk);
        int kb = hasb ? klist[i + 1] : ka;
        float sb = hasb ? 1.0f : 0.0f;
        f2 caA = pp[ka * Dc];                  // dwordx2 {c,A}, coalesced
        f2 caB = pp[kb * Dc];
        f4 peA = peT[ka];                      // LDS b128 broadcast
        f4 peB = peT[kb];
        peB *= sb;                             // zero the duplicate tail
        #pragma unroll
        for (int p = 0; p < 2; ++p) {
            f2 ep = e2[p], nap = na2[p];
            f2 vA = fma2(ep, splat2(caA[1]), one2);
            f2 vB = fma2(ep, splat2(caB[1]), one2);
            f2 fA = fma2(nap, splat2(caA[0]), xp[p]);
            f2 fB = fma2(nap, splat2(caB[0]), xp[p]);
            f2 uA = (f2){peA[2*p], peA[2*p+1]} * fA;
            f2 uB = (f2){peB[2*p], peB[2*p+1]} * fB;
            f2 den = vA * vB;
            f2 num = fma2(uB, vA, uA * vB);
            O[p] = fma2(num, rcp2(den), O[p]);
        }
    }

    #pragma unroll
    for (int p = 0; p < 2; ++p) {
        #pragma unroll
        for (int j = 0; j < 2; ++j) {
            int g = 2 * p + j;
            float Z = wsum[g][0] + wsum[g][1];
            out[(b0 + g) * Dc + tid] = sg[g] * __builtin_amdgcn_rcpf(Z) * O[p][j];
        }
    }
}

extern "C" void kernel_launch(void* const* d_in, const int* in_sizes, int n_in,
                              void* d_out, int out_size, void* d_ws, size_t ws_size,
                              hipStream_t stream) {
    const float* x       = (const float*)d_in[0];
    const float* t       = (const float*)d_in[1];
    const float* centers = (const float*)d_in[2];
    const float* stds    = (const float*)d_in[3];
    const float* weights = (const float*)d_in[4];
    float* outp = (float*)d_out;

    float* CA8 = (float*)d_ws;                    // [D/4][K][8]  (256 KB)
    f2*    P2  = (f2*)(CA8 + Kc * Dc * 2);        // [K][D] {c,A} (256 KB)

    const int B = in_sizes[1];                    // 4096

    prep_kernel<<<(Kc * Dc + 255) / 256, 256, 0, stream>>>(centers, stds, CA8, P2);
    score_kernel<<<B / G, 256, 0, stream>>>(x, t, weights, CA8, P2, outp);
}

// Round 6
// 104.533 us; speedup vs baseline: 1.1305x; 1.0216x over previous
//
#include <hip/hip_runtime.h>
#include <math.h>

// B=4096, K=128, D=256.
// out[b,d] = sqrt(1-e) * sum_k p_k * (x - a*c)/var,  var = 1 + e*(s^2-1)
// lp_k = -0.5*S1 - 128*ln2*S2 + ln w_k  (k-uniform const dropped)
//   S1 = sum_d diff^2/var, S2 = sum_d log2(var)
// Packed 2xf32 math (f2 lanes = 2 batch rows), 4-way combined division
// (1 rcp / 4 d-tuples), 1 log per 16 d.
// R6: 512-thread blocks, G=4, grid=1024 -> 4 blocks/CU x 8 waves = 32
// waves/CU (R3 had 16) at IDENTICAL table traffic; pass 1 splits D 4 ways,
// pass 2 splits K 2 ways + LDS combine. (R4: more blocks doubled L2 traffic,
// regressed. R5: data-dependent survivor pass 2 beat compiler scheduling,
// regressed.)

constexpr int Kc = 128;
constexpr int Dc = 256;
constexpr int G  = 4;   // batch rows per block (2 f2 pairs)

typedef float f2 __attribute__((ext_vector_type(2)));
typedef float f4 __attribute__((ext_vector_type(4)));

static __device__ __forceinline__ f2 fma2(f2 a, f2 b, f2 c) {
    return __builtin_elementwise_fma(a, b, c);
}
static __device__ __forceinline__ f2 splat2(float s) { return (f2){s, s}; }
static __device__ __forceinline__ f2 rcp2(f2 a) {
    return (f2){__builtin_amdgcn_rcpf(a[0]), __builtin_amdgcn_rcpf(a[1])};
}

// prep: CA8[(d>>2)][k][8] = {c0..c3, A0..A3} (pass-1, transposed);
//       P2[k*Dc+d] = {c, A} (pass-2), A = s^2-1.
__global__ void prep_kernel(const float* __restrict__ centers,
                            const float* __restrict__ stds,
                            float* __restrict__ CA8, f2* __restrict__ P2) {
    int idx = blockIdx.x * blockDim.x + threadIdx.x;   // k*Dc + d
    if (idx >= Kc * Dc) return;
    int k = idx >> 8;
    int d = idx & (Dc - 1);
    float c = centers[idx];
    float s = stds[idx];
    float A = s * s - 1.0f;
    int o = (d >> 2) * (Kc * 8) + k * 8 + (d & 3);
    CA8[o]     = c;
    CA8[o + 4] = A;
    P2[idx] = (f2){c, A};
}

__global__ __launch_bounds__(512, 8) void score_kernel(
    const float* __restrict__ x, const float* __restrict__ t,
    const float* __restrict__ weights,
    const float* __restrict__ CA8, const f2* __restrict__ P2,
    float* __restrict__ out)
{
    const int b0  = blockIdx.x * G;
    const int tid = threadIdx.x;

    __shared__ __align__(16) f4 xT[Dc];        // xT[d] = {x_g0..x_g3}   4 KB
    __shared__ float part1[G][4][Kc];          // pass-1 S1 partials     8 KB
    __shared__ float partL[G][4][Kc];          // pass-1 S2 partials     8 KB
    __shared__ __align__(16) f4 peT[Kc];       // softmax numerators     2 KB
    __shared__ __align__(16) f4 Opart[Dc];     // pass-2 upper-half O    4 KB
    __shared__ float wmax[G][2];
    __shared__ float wsum[G][2];

    // per-row scalars (uniform; cheap per thread)
    float e[G], na[G], sg[G];
    #pragma unroll
    for (int g = 0; g < G; ++g) {
        float tt = t[b0 + g];
        float Bt = fmaf(9.95f * tt, tt, 0.1f * tt);
        float ee = __expf(-Bt);
        e[g]  = ee;
        na[g] = -sqrtf(ee);
        sg[g] = sqrtf(1.0f - ee);
    }
    f2 e2[2]  = {{e[0], e[1]}, {e[2], e[3]}};
    f2 na2[2] = {{na[0], na[1]}, {na[2], na[3]}};
    const f2 one2 = {1.0f, 1.0f};

    if (tid < Dc) {
        f4 xv;
        #pragma unroll
        for (int g = 0; g < G; ++g) xv[g] = x[(b0 + g) * Dc + tid];
        xT[tid] = xv;
    }
    __syncthreads();

    // ---------------- pass 1: thread = (k, quarter-of-D), 64 d each ----------------
    const int kk    = tid & (Kc - 1);
    const int qtr   = tid >> 7;                // 0..3
    const int dbase = qtr * (Dc / 4);

    const f4* xTv = (const f4*)(&xT[0]);

    f2 acc1[2] = {{0.f, 0.f}, {0.f, 0.f}};
    float accL[G] = {0.f, 0.f, 0.f, 0.f};

    for (int grp = 0; grp < 4; ++grp) {        // 4 groups x 4 quads x 4 d = 64 d
        f2 prod[2] = {{1.f, 1.f}, {1.f, 1.f}};
        #pragma unroll
        for (int q = 0; q < 4; ++q) {
            const int d0 = dbase + (grp * 4 + q) * 4;
            const float* base = CA8 + ((size_t)(d0 >> 2) * Kc + kk) * 8;
            f4 c4 = *(const f4*)base;          // dwordx4, coalesced over kk
            f4 A4 = *(const f4*)(base + 4);    // same addr + imm 16
            f4 xv0 = xTv[d0 + 0];              // LDS b128 broadcast (d uniform)
            f4 xv1 = xTv[d0 + 1];
            f4 xv2 = xTv[d0 + 2];
            f4 xv3 = xTv[d0 + 3];
            #pragma unroll
            for (int p = 0; p < 2; ++p) {
                f2 ep = e2[p], nap = na2[p];
                f2 x0 = {xv0[2*p], xv0[2*p+1]};
                f2 x1 = {xv1[2*p], xv1[2*p+1]};
                f2 x2 = {xv2[2*p], xv2[2*p+1]};
                f2 x3 = {xv3[2*p], xv3[2*p+1]};
                f2 v0 = fma2(ep, splat2(A4[0]), one2);   // var in [0.25,1]
                f2 v1 = fma2(ep, splat2(A4[1]), one2);
                f2 v2 = fma2(ep, splat2(A4[2]), one2);
                f2 v3 = fma2(ep, splat2(A4[3]), one2);
                f2 f0 = fma2(nap, splat2(c4[0]), x0);
                f2 f1 = fma2(nap, splat2(c4[1]), x1);
                f2 f2_ = fma2(nap, splat2(c4[2]), x2);
                f2 f3 = fma2(nap, splat2(c4[3]), x3);
                f2 s0 = f0 * f0, s1 = f1 * f1, s2 = f2_ * f2_, s3 = f3 * f3;
                f2 d01 = v0 * v1, d23 = v2 * v3;
                f2 n01 = fma2(s1, v0, s0 * v1);
                f2 n23 = fma2(s3, v2, s2 * v3);
                f2 den = d01 * d23;                      // >= 0.25^4
                f2 num = fma2(n23, d01, n01 * d23);
                acc1[p] = fma2(num, rcp2(den), acc1[p]);
                prod[p] = prod[p] * den;
            }
        }
        accL[0] += __log2f(prod[0][0]);        // 1 log per 16 d per g
        accL[1] += __log2f(prod[0][1]);
        accL[2] += __log2f(prod[1][0]);
        accL[3] += __log2f(prod[1][1]);
    }
    #pragma unroll
    for (int p = 0; p < 2; ++p) {
        part1[2*p  ][qtr][kk] = acc1[p][0];
        part1[2*p+1][qtr][kk] = acc1[p][1];
    }
    #pragma unroll
    for (int g = 0; g < G; ++g)
        partL[g][qtr][kk] = accL[g];
    __syncthreads();

    // ---------------- softmax over k (threads < K, 2 full waves) ----------------
    float lpv[G];
    if (tid < Kc) {
        float lw = __logf(weights[tid]);
        #pragma unroll
        for (int g = 0; g < G; ++g) {
            float S1 = (part1[g][0][tid] + part1[g][1][tid])
                     + (part1[g][2][tid] + part1[g][3][tid]);
            float S2 = (partL[g][0][tid] + partL[g][1][tid])
                     + (partL[g][2][tid] + partL[g][3][tid]);
            lpv[g] = fmaf(-0.5f, S1, fmaf(-88.72283911167299f, S2, lw)); // 128*ln2
            float m = lpv[g];
            #pragma unroll
            for (int off = 32; off > 0; off >>= 1)
                m = fmaxf(m, __shfl_xor(m, off, 64));
            if ((tid & 63) == 0) wmax[g][tid >> 6] = m;
        }
    }
    __syncthreads();
    if (tid < Kc) {
        f4 pe4;
        #pragma unroll
        for (int g = 0; g < G; ++g) {
            float m  = fmaxf(wmax[g][0], wmax[g][1]);
            float pe = __expf(lpv[g] - m);
            pe4[g] = pe;
            float s = pe;
            #pragma unroll
            for (int off = 32; off > 0; off >>= 1)
                s += __shfl_xor(s, off, 64);
            if ((tid & 63) == 0) wsum[g][tid >> 6] = s;
        }
        peT[tid] = pe4;                        // unnormalized; 1/Z in epilogue
    }
    __syncthreads();

    // ---------------- pass 2: thread = (d, half-of-K), 64 k each ----------------
    const int dd = tid & (Dc - 1);
    const int kh = tid >> 8;                   // 0..1

    f4 xv = xT[dd];
    f2 xp[2] = {{xv[0], xv[1]}, {xv[2], xv[3]}};
    f2 O[2] = {{0.f, 0.f}, {0.f, 0.f}};
    const f4* peTv = (const f4*)(&peT[0]);
    const f2* pp = P2 + dd;

    for (int kq = kh * 16; kq < kh * 16 + 16; ++kq) {
        const int k0 = kq * 4;
        f2 ca0 = pp[(k0 + 0) * Dc];            // dwordx2 {c,A}, coalesced
        f2 ca1 = pp[(k0 + 1) * Dc];
        f2 ca2 = pp[(k0 + 2) * Dc];
        f2 ca3 = pp[(k0 + 3) * Dc];
        f4 pa = peTv[(k0 >> 1) + 0];           // LDS b128 broadcast
        f4 pb = peTv[(k0 >> 1) + 1];
        #pragma unroll
        for (int p = 0; p < 2; ++p) {
            f2 ep = e2[p], nap = na2[p];
            f2 v0 = fma2(ep, splat2(ca0[1]), one2);
            f2 v1 = fma2(ep, splat2(ca1[1]), one2);
            f2 v2 = fma2(ep, splat2(ca2[1]), one2);
            f2 v3 = fma2(ep, splat2(ca3[1]), one2);
            f2 f0 = fma2(nap, splat2(ca0[0]), xp[p]);
            f2 f1 = fma2(nap, splat2(ca1[0]), xp[p]);
            f2 f2_ = fma2(nap, splat2(ca2[0]), xp[p]);
            f2 f3 = fma2(nap, splat2(ca3[0]), xp[p]);
            f2 u0 = (f2){pa[2*p], pa[2*p+1]} * f0;
            f2 u1 = (f2){pa[2*p], pa[2*p+1]};  // placeholder overwritten below
            u1 = (f2){pa[2*p], pa[2*p+1]};
            // correct per-k numerators:
            u1 = (f2){pb[0], pb[0]};           // (will be fixed just below)
            // -- expanded explicitly to avoid aliasing mistakes --
            f2 w0 = {pa[2*p], pa[2*p+1]};
            f2 w1 = {pa[2*p], pa[2*p+1]};
            (void)u1; (void)w1;
            // NOTE: pa holds pe for k0,k0+1 (g-pairs); pb for k0+2,k0+3.
            f2 q0 = {pa[2*p], pa[2*p+1]};      // pe[k0]   ... wrong layout guard
            (void)q0; (void)w0; (void)u0;
            // Use direct LDS scalar f4 reads instead (simple and correct):
            f4 peA = peT[k0 + 0];
            f4 peB = peT[k0 + 1];
            f4 peC = peT[k0 + 2];
            f4 peD = peT[k0 + 3];
            f2 uu0 = (f2){peA[2*p], peA[2*p+1]} * f0;
            f2 uu1 = (f2){peB[2*p], peB[2*p+1]} * f1;
            f2 uu2 = (f2){peC[2*p], peC[2*p+1]} * f2_;
            f2 uu3 = (f2){peD[2*p], peD[2*p+1]} * f3;
            f2 d01 = v0 * v1, d23 = v2 * v3;
            f2 n01 = fma2(uu1, v0, uu0 * v1);
            f2 n23 = fma2(uu3, v2, uu2 * v3);
            f2 den = d01 * d23;
            f2 num = fma2(n23, d01, n01 * d23);
            O[p] = fma2(num, rcp2(den), O[p]);
        }
    }

    if (kh == 1) {
        Opart[dd] = (f4){O[0][0], O[0][1], O[1][0], O[1][1]};
    }
    __syncthreads();

    if (tid < Dc) {
        f4 Ou = Opart[tid];
        #pragma unroll
        for (int p = 0; p < 2; ++p) {
            #pragma unroll
            for (int j = 0; j < 2; ++j) {
                int g = 2 * p + j;
                float Z = wsum[g][0] + wsum[g][1];
                float Osum = O[p][j] + Ou[2 * p + j];
                out[(b0 + g) * Dc + tid] = sg[g] * __builtin_amdgcn_rcpf(Z) * Osum;
            }
        }
    }
}

extern "C" void kernel_launch(void* const* d_in, const int* in_sizes, int n_in,
                              void* d_out, int out_size, void* d_ws, size_t ws_size,
                              hipStream_t stream) {
    const float* x       = (const float*)d_in[0];
    const float* t       = (const float*)d_in[1];
    const float* centers = (const float*)d_in[2];
    const float* stds    = (const float*)d_in[3];
    const float* weights = (const float*)d_in[4];
    float* outp = (float*)d_out;

    float* CA8 = (float*)d_ws;                    // [D/4][K][8]  (256 KB)
    f2*    P2  = (f2*)(CA8 + Kc * Dc * 2);        // [K][D] {c,A} (256 KB)

    const int B = in_sizes[1];                    // 4096

    prep_kernel<<<(Kc * Dc + 255) / 256, 256, 0, stream>>>(centers, stds, CA8, P2);
    score_kernel<<<B / G, 512, 0, stream>>>(x, t, weights, CA8, P2, outp);
}